// Round 1
// baseline (104.619 us; speedup 1.0000x reference)
//
#include <hip/hip_runtime.h>

#define EPSF 1e-5f

namespace {
constexpr int B = 64, D = 20000, C = 16, H = 64, EH = 128, L = 32;
constexpr int KIN = 1 + C;                      // 17
constexpr int CHUNK = 256;                      // d's per block
constexpr int NCHUNK = (D + CHUNK - 1) / CHUNK; // 79
}

// Kernel 1: per-row pointnet (Linear->LN->ReLU ->Linear->LN->ReLU), masked,
// with deterministic per-block partial pooling.
__global__ __launch_bounds__(256) void k_rows(
    const float* __restrict__ x, const int* __restrict__ mask,
    const float* __restrict__ fe,
    const float* __restrict__ W1, const float* __restrict__ b1,
    const float* __restrict__ g1, const float* __restrict__ be1,
    const float* __restrict__ W2, const float* __restrict__ b2,
    const float* __restrict__ g2, const float* __restrict__ be2,
    float* __restrict__ part,    // [B][NCHUNK][C]
    float* __restrict__ partc)   // [B][NCHUNK]
{
    const int b = blockIdx.y;
    const int chunk = blockIdx.x;
    const int d = chunk * CHUNK + threadIdx.x;
    const bool valid = d < D;

    float hin[KIN];
    float m = 0.f;
    if (valid) {
        m = (float)mask[(size_t)b * D + d];
        hin[0] = x[(size_t)b * D + d];
        const float4* fr = reinterpret_cast<const float4*>(fe + (size_t)d * C);
        float4 f0 = fr[0], f1 = fr[1], f2 = fr[2], f3 = fr[3];
        hin[1]  = f0.x; hin[2]  = f0.y; hin[3]  = f0.z; hin[4]  = f0.w;
        hin[5]  = f1.x; hin[6]  = f1.y; hin[7]  = f1.z; hin[8]  = f1.w;
        hin[9]  = f2.x; hin[10] = f2.y; hin[11] = f2.z; hin[12] = f2.w;
        hin[13] = f3.x; hin[14] = f3.y; hin[15] = f3.z; hin[16] = f3.w;
    } else {
        #pragma unroll
        for (int k = 0; k < KIN; ++k) hin[k] = 0.f;
    }

    // Layer 1: t1 = hin @ W1 + b1   (weights read with uniform index -> s_load)
    float t1[H];
    #pragma unroll
    for (int h = 0; h < H; ++h) t1[h] = b1[h];
    #pragma unroll
    for (int k = 0; k < KIN; ++k) {
        const float v = hin[k];
        #pragma unroll
        for (int h = 0; h < H; ++h)
            t1[h] = fmaf(v, W1[k * H + h], t1[h]);
    }
    // LN over H (in-lane)
    float s = 0.f, ss = 0.f;
    #pragma unroll
    for (int h = 0; h < H; ++h) { s += t1[h]; ss = fmaf(t1[h], t1[h], ss); }
    const float mean1 = s * (1.f / H);
    const float var1  = fmaxf(ss * (1.f / H) - mean1 * mean1, 0.f);
    const float rstd1 = rsqrtf(var1 + EPSF);

    // Layer 2: a2 = relu(LN(t1)) @ W2 + b2
    float a2[C];
    #pragma unroll
    for (int c = 0; c < C; ++c) a2[c] = b2[c];
    #pragma unroll
    for (int h = 0; h < H; ++h) {
        float t = (t1[h] - mean1) * rstd1;
        float r = fmaxf(fmaf(t, g1[h], be1[h]), 0.f);
        #pragma unroll
        for (int c = 0; c < C; ++c)
            a2[c] = fmaf(r, W2[h * C + c], a2[c]);
    }
    // LN over C (in-lane), ReLU, mask
    float s2 = 0.f, ss2 = 0.f;
    #pragma unroll
    for (int c = 0; c < C; ++c) { s2 += a2[c]; ss2 = fmaf(a2[c], a2[c], ss2); }
    const float mean2 = s2 * (1.f / C);
    const float var2  = fmaxf(ss2 * (1.f / C) - mean2 * mean2, 0.f);
    const float rstd2 = rsqrtf(var2 + EPSF);
    #pragma unroll
    for (int c = 0; c < C; ++c) {
        float t = (a2[c] - mean2) * rstd2;
        a2[c] = fmaxf(fmaf(t, g2[c], be2[c]), 0.f) * m;
    }

    // Deterministic wave butterfly reduction (64 lanes)
    #pragma unroll
    for (int off = 32; off > 0; off >>= 1) {
        #pragma unroll
        for (int c = 0; c < C; ++c)
            a2[c] += __shfl_xor(a2[c], off, 64);
        m += __shfl_xor(m, off, 64);
    }

    __shared__ float wsum[4][C];
    __shared__ float wcnt[4];
    const int wid  = threadIdx.x >> 6;
    const int lane = threadIdx.x & 63;
    if (lane == 0) {
        #pragma unroll
        for (int c = 0; c < C; ++c) wsum[wid][c] = a2[c];
        wcnt[wid] = m;
    }
    __syncthreads();
    if (threadIdx.x < C) {
        float v = wsum[0][threadIdx.x] + wsum[1][threadIdx.x] +
                  wsum[2][threadIdx.x] + wsum[3][threadIdx.x];
        part[((size_t)b * NCHUNK + chunk) * C + threadIdx.x] = v;
    } else if (threadIdx.x == C) {
        partc[(size_t)b * NCHUNK + chunk] = wcnt[0] + wcnt[1] + wcnt[2] + wcnt[3];
    }
}

// Kernel 2: per-batch pooled vector -> encoder MLP (16->128->64), split mu/logvar.
__global__ __launch_bounds__(EH) void k_enc(
    const float* __restrict__ part, const float* __restrict__ partc,
    const float* __restrict__ We1, const float* __restrict__ bb1,
    const float* __restrict__ gg1, const float* __restrict__ bbe1,
    const float* __restrict__ We2, const float* __restrict__ bb2,
    const float* __restrict__ gg2, const float* __restrict__ bbe2,
    float* __restrict__ out)
{
    const int b = blockIdx.x;
    const int t = threadIdx.x;
    __shared__ float cc[C];
    __shared__ float stats[2];
    __shared__ float inv_sh;
    __shared__ float buf[EH];
    __shared__ float buf2[2 * L];

    if (t < C) {
        float s = 0.f;
        for (int j = 0; j < NCHUNK; ++j)
            s += part[((size_t)b * NCHUNK + j) * C + t];
        cc[t] = s;
    } else if (t == C) {
        float s = 0.f;
        for (int j = 0; j < NCHUNK; ++j)
            s += partc[(size_t)b * NCHUNK + j];
        inv_sh = 1.f / fmaxf(s, 1.f);
    }
    __syncthreads();
    const float inv = inv_sh;

    // e1 = c @ We1 + bb1  (thread t owns column t of EH=128)
    float v1 = bb1[t];
    #pragma unroll
    for (int c = 0; c < C; ++c)
        v1 = fmaf(cc[c] * inv, We1[c * EH + t], v1);
    buf[t] = v1;
    __syncthreads();
    if (t == 0) {
        float s = 0.f, ss = 0.f;
        for (int j = 0; j < EH; ++j) { s += buf[j]; ss = fmaf(buf[j], buf[j], ss); }
        float mn = s * (1.f / EH);
        float vr = fmaxf(ss * (1.f / EH) - mn * mn, 0.f);
        stats[0] = mn; stats[1] = rsqrtf(vr + EPSF);
    }
    __syncthreads();
    float e1 = fmaxf(fmaf((v1 - stats[0]) * stats[1], gg1[t], bbe1[t]), 0.f);
    __syncthreads();
    buf[t] = e1;
    __syncthreads();

    // e2 = e1 @ We2 + bb2  (threads t < 64)
    float v2 = 0.f;
    if (t < 2 * L) {
        v2 = bb2[t];
        #pragma unroll
        for (int h = 0; h < EH; ++h)
            v2 = fmaf(buf[h], We2[h * (2 * L) + t], v2);
        buf2[t] = v2;
    }
    __syncthreads();
    if (t == 0) {
        float s = 0.f, ss = 0.f;
        for (int j = 0; j < 2 * L; ++j) { s += buf2[j]; ss = fmaf(buf2[j], buf2[j], ss); }
        float mn = s * (1.f / (2 * L));
        float vr = fmaxf(ss * (1.f / (2 * L)) - mn * mn, 0.f);
        stats[0] = mn; stats[1] = rsqrtf(vr + EPSF);
    }
    __syncthreads();
    if (t < 2 * L) {
        float e2 = fmaxf(fmaf((v2 - stats[0]) * stats[1], gg2[t], bbe2[t]), 0.f);
        if (t < L) out[(size_t)b * L + t]                       = e2;  // mu
        else       out[(size_t)B * L + (size_t)b * L + (t - L)] = e2;  // logvar
    }
}

extern "C" void kernel_launch(void* const* d_in, const int* in_sizes, int n_in,
                              void* d_out, int out_size, void* d_ws, size_t ws_size,
                              hipStream_t stream) {
    const float* x    = (const float*)d_in[0];
    const int*   mask = (const int*)d_in[1];
    const float* fe   = (const float*)d_in[2];
    const float* W1   = (const float*)d_in[3];
    const float* b1   = (const float*)d_in[4];
    const float* g1   = (const float*)d_in[5];
    const float* be1  = (const float*)d_in[6];
    const float* W2   = (const float*)d_in[7];
    const float* b2   = (const float*)d_in[8];
    const float* g2   = (const float*)d_in[9];
    const float* be2  = (const float*)d_in[10];
    const float* We1  = (const float*)d_in[11];
    const float* bb1  = (const float*)d_in[12];
    const float* gg1  = (const float*)d_in[13];
    const float* bbe1 = (const float*)d_in[14];
    const float* We2  = (const float*)d_in[15];
    const float* bb2  = (const float*)d_in[16];
    const float* gg2  = (const float*)d_in[17];
    const float* bbe2 = (const float*)d_in[18];
    float* out = (float*)d_out;

    float* part  = (float*)d_ws;                       // B*NCHUNK*C floats
    float* partc = part + (size_t)B * NCHUNK * C;      // B*NCHUNK floats

    dim3 grid1(NCHUNK, B);
    hipLaunchKernelGGL(k_rows, grid1, dim3(CHUNK), 0, stream,
                       x, mask, fe, W1, b1, g1, be1, W2, b2, g2, be2, part, partc);
    hipLaunchKernelGGL(k_enc, dim3(B), dim3(EH), 0, stream,
                       part, partc, We1, bb1, gg1, bbe1, We2, bb2, gg2, bbe2, out);
}

// Round 2
// 68.096 us; speedup vs baseline: 1.5364x; 1.5364x over previous
//
#include <hip/hip_runtime.h>

#define EPSF 1e-5f

namespace {
constexpr int B = 64, D = 20000, C = 16, H = 64, EH = 128, L = 32;
constexpr int KIN = 1 + C;                      // 17
constexpr int CHUNK = 256;                      // entries per block
constexpr int NCHUNK = (D + CHUNK - 1) / CHUNK; // 79
}

// ---------- Phase A: per-(batch,chunk) observed-count ----------
__global__ __launch_bounds__(256) void k_count(
    const int* __restrict__ mask, int* __restrict__ chunkpop)
{
    const int b = blockIdx.y, j = blockIdx.x;
    const int d = j * CHUNK + threadIdx.x;
    const int mv = (d < D) ? mask[(size_t)b * D + d] : 0;
    const unsigned long long bal = __ballot(mv != 0);
    __shared__ int ws[4];
    const int lane = threadIdx.x & 63, wid = threadIdx.x >> 6;
    if (lane == 0) ws[wid] = __popcll(bal);
    __syncthreads();
    if (threadIdx.x == 0)
        chunkpop[b * NCHUNK + j] = ws[0] + ws[1] + ws[2] + ws[3];
}

// ---------- Phase B: per-batch exclusive scan of chunk counts ----------
__global__ __launch_bounds__(128) void k_scan(
    const int* __restrict__ chunkpop, int* __restrict__ chunkoff,
    int* __restrict__ cnt)
{
    const int b = blockIdx.x;
    const int t = threadIdx.x;
    __shared__ int sbuf[128];
    const int v = (t < NCHUNK) ? chunkpop[b * NCHUNK + t] : 0;
    sbuf[t] = v;
    __syncthreads();
    #pragma unroll
    for (int off = 1; off < 128; off <<= 1) {
        int add = (t >= off) ? sbuf[t - off] : 0;
        __syncthreads();
        sbuf[t] += add;
        __syncthreads();
    }
    if (t < NCHUNK) chunkoff[b * NCHUNK + t] = sbuf[t] - v;  // exclusive
    if (t == 0) cnt[b] = sbuf[NCHUNK - 1];
}

// ---------- Phase C: scatter observed d-indices (deterministic order) ----------
__global__ __launch_bounds__(256) void k_scatter(
    const int* __restrict__ mask, const int* __restrict__ chunkoff,
    unsigned short* __restrict__ cd)
{
    const int b = blockIdx.y, j = blockIdx.x;
    const int d = j * CHUNK + threadIdx.x;
    const int mv = (d < D) ? mask[(size_t)b * D + d] : 0;
    const unsigned long long bal = __ballot(mv != 0);
    const int lane = threadIdx.x & 63, wid = threadIdx.x >> 6;
    __shared__ int ws[4];
    if (lane == 0) ws[wid] = __popcll(bal);
    __syncthreads();
    int woff = 0;
    for (int w = 0; w < wid; ++w) woff += ws[w];
    const int pre = __popcll(bal & ((1ull << lane) - 1ull));
    if (mv)
        cd[(size_t)b * D + chunkoff[b * NCHUNK + j] + woff + pre] =
            (unsigned short)d;
}

// ---------- Main per-row pointnet over COMPACTED entries ----------
__global__ __launch_bounds__(256, 4) void k_rows(
    const float* __restrict__ x, const unsigned short* __restrict__ cd,
    const int* __restrict__ cnt, const float* __restrict__ fe,
    const float* __restrict__ W1, const float* __restrict__ b1,
    const float* __restrict__ g1, const float* __restrict__ be1,
    const float* __restrict__ W2, const float* __restrict__ b2,
    const float* __restrict__ g2, const float* __restrict__ be2,
    float* __restrict__ part)    // [B][NCHUNK][C]
{
    const int b = blockIdx.y;
    const int chunk = blockIdx.x;
    const int cbase = chunk * CHUNK;
    const int n = cnt[b];
    if (cbase >= n) return;      // nothing for this block

    const int i = cbase + threadIdx.x;
    const bool valid = i < n;

    float hin[KIN];
    if (valid) {
        const int d = cd[(size_t)b * D + i];
        hin[0] = x[(size_t)b * D + d];
        const float4* fr = reinterpret_cast<const float4*>(fe + (size_t)d * C);
        float4 f0 = fr[0], f1 = fr[1], f2 = fr[2], f3 = fr[3];
        hin[1]  = f0.x; hin[2]  = f0.y; hin[3]  = f0.z; hin[4]  = f0.w;
        hin[5]  = f1.x; hin[6]  = f1.y; hin[7]  = f1.z; hin[8]  = f1.w;
        hin[9]  = f2.x; hin[10] = f2.y; hin[11] = f2.z; hin[12] = f2.w;
        hin[13] = f3.x; hin[14] = f3.y; hin[15] = f3.z; hin[16] = f3.w;
    } else {
        #pragma unroll
        for (int k = 0; k < KIN; ++k) hin[k] = 0.f;
    }

    // Layer 1: t1 = hin @ W1 + b1   (uniform weight index -> scalar loads)
    float t1[H];
    #pragma unroll
    for (int h = 0; h < H; ++h) t1[h] = b1[h];
    #pragma unroll
    for (int k = 0; k < KIN; ++k) {
        const float v = hin[k];
        #pragma unroll
        for (int h = 0; h < H; ++h)
            t1[h] = fmaf(v, W1[k * H + h], t1[h]);
    }
    // LN over H (in-lane), 4-way accumulator tree for ILP
    float s0 = 0.f, s1 = 0.f, s2 = 0.f, s3 = 0.f;
    float q0 = 0.f, q1 = 0.f, q2 = 0.f, q3 = 0.f;
    #pragma unroll
    for (int h = 0; h < H; h += 4) {
        s0 += t1[h];     q0 = fmaf(t1[h],     t1[h],     q0);
        s1 += t1[h + 1]; q1 = fmaf(t1[h + 1], t1[h + 1], q1);
        s2 += t1[h + 2]; q2 = fmaf(t1[h + 2], t1[h + 2], q2);
        s3 += t1[h + 3]; q3 = fmaf(t1[h + 3], t1[h + 3], q3);
    }
    const float s  = (s0 + s1) + (s2 + s3);
    const float ss = (q0 + q1) + (q2 + q3);
    const float mean1 = s * (1.f / H);
    const float var1  = fmaxf(ss * (1.f / H) - mean1 * mean1, 0.f);
    const float rstd1 = rsqrtf(var1 + EPSF);

    // Layer 2: a2 = relu(LN(t1)) @ W2 + b2
    float a2[C];
    #pragma unroll
    for (int c = 0; c < C; ++c) a2[c] = b2[c];
    #pragma unroll
    for (int h = 0; h < H; ++h) {
        float t = (t1[h] - mean1) * rstd1;
        float r = fmaxf(fmaf(t, g1[h], be1[h]), 0.f);
        #pragma unroll
        for (int c = 0; c < C; ++c)
            a2[c] = fmaf(r, W2[h * C + c], a2[c]);
    }
    // LN over C, ReLU, zero invalid lanes
    float u0 = 0.f, u1 = 0.f, v0 = 0.f, v1 = 0.f;
    #pragma unroll
    for (int c = 0; c < C; c += 2) {
        u0 += a2[c];     v0 = fmaf(a2[c],     a2[c],     v0);
        u1 += a2[c + 1]; v1 = fmaf(a2[c + 1], a2[c + 1], v1);
    }
    const float s2n = u0 + u1, ss2 = v0 + v1;
    const float mean2 = s2n * (1.f / C);
    const float var2  = fmaxf(ss2 * (1.f / C) - mean2 * mean2, 0.f);
    const float rstd2 = rsqrtf(var2 + EPSF);
    const float vm = valid ? 1.f : 0.f;
    #pragma unroll
    for (int c = 0; c < C; ++c) {
        float t = (a2[c] - mean2) * rstd2;
        a2[c] = fmaxf(fmaf(t, g2[c], be2[c]), 0.f) * vm;
    }

    // Deterministic wave butterfly reduction (64 lanes)
    #pragma unroll
    for (int off = 32; off > 0; off >>= 1) {
        #pragma unroll
        for (int c = 0; c < C; ++c)
            a2[c] += __shfl_xor(a2[c], off, 64);
    }

    __shared__ float wsum[4][C];
    const int wid  = threadIdx.x >> 6;
    const int lane = threadIdx.x & 63;
    if (lane == 0) {
        #pragma unroll
        for (int c = 0; c < C; ++c) wsum[wid][c] = a2[c];
    }
    __syncthreads();
    if (threadIdx.x < C) {
        float v = wsum[0][threadIdx.x] + wsum[1][threadIdx.x] +
                  wsum[2][threadIdx.x] + wsum[3][threadIdx.x];
        part[((size_t)b * NCHUNK + chunk) * C + threadIdx.x] = v;
    }
}

// ---------- Encoder MLP per batch ----------
__global__ __launch_bounds__(EH) void k_enc(
    const float* __restrict__ part, const int* __restrict__ cnt,
    const float* __restrict__ We1, const float* __restrict__ bb1,
    const float* __restrict__ gg1, const float* __restrict__ bbe1,
    const float* __restrict__ We2, const float* __restrict__ bb2,
    const float* __restrict__ gg2, const float* __restrict__ bbe2,
    float* __restrict__ out)
{
    const int b = blockIdx.x;
    const int t = threadIdx.x;
    __shared__ float cc[C];
    __shared__ float stats[2];
    __shared__ float buf[EH];
    __shared__ float buf2[2 * L];

    const int n = cnt[b];
    const int nch = (n + CHUNK - 1) / CHUNK;
    if (t < C) {
        float s = 0.f;
        for (int j = 0; j < nch; ++j)
            s += part[((size_t)b * NCHUNK + j) * C + t];
        cc[t] = s;
    }
    __syncthreads();
    const float inv = 1.f / fmaxf((float)n, 1.f);

    // e1 = c @ We1 + bb1  (thread t owns column t of EH=128)
    float v1 = bb1[t];
    #pragma unroll
    for (int c = 0; c < C; ++c)
        v1 = fmaf(cc[c] * inv, We1[c * EH + t], v1);
    buf[t] = v1;
    __syncthreads();
    if (t == 0) {
        float s = 0.f, ss = 0.f;
        for (int j = 0; j < EH; ++j) { s += buf[j]; ss = fmaf(buf[j], buf[j], ss); }
        float mn = s * (1.f / EH);
        float vr = fmaxf(ss * (1.f / EH) - mn * mn, 0.f);
        stats[0] = mn; stats[1] = rsqrtf(vr + EPSF);
    }
    __syncthreads();
    float e1 = fmaxf(fmaf((v1 - stats[0]) * stats[1], gg1[t], bbe1[t]), 0.f);
    __syncthreads();
    buf[t] = e1;
    __syncthreads();

    // e2 = e1 @ We2 + bb2  (threads t < 64)
    float v2 = 0.f;
    if (t < 2 * L) {
        v2 = bb2[t];
        #pragma unroll
        for (int h = 0; h < EH; ++h)
            v2 = fmaf(buf[h], We2[h * (2 * L) + t], v2);
        buf2[t] = v2;
    }
    __syncthreads();
    if (t == 0) {
        float s = 0.f, ss = 0.f;
        for (int j = 0; j < 2 * L; ++j) { s += buf2[j]; ss = fmaf(buf2[j], buf2[j], ss); }
        float mn = s * (1.f / (2 * L));
        float vr = fmaxf(ss * (1.f / (2 * L)) - mn * mn, 0.f);
        stats[0] = mn; stats[1] = rsqrtf(vr + EPSF);
    }
    __syncthreads();
    if (t < 2 * L) {
        float e2 = fmaxf(fmaf((v2 - stats[0]) * stats[1], gg2[t], bbe2[t]), 0.f);
        if (t < L) out[(size_t)b * L + t]                       = e2;  // mu
        else       out[(size_t)B * L + (size_t)b * L + (t - L)] = e2;  // logvar
    }
}

extern "C" void kernel_launch(void* const* d_in, const int* in_sizes, int n_in,
                              void* d_out, int out_size, void* d_ws, size_t ws_size,
                              hipStream_t stream) {
    const float* x    = (const float*)d_in[0];
    const int*   mask = (const int*)d_in[1];
    const float* fe   = (const float*)d_in[2];
    const float* W1   = (const float*)d_in[3];
    const float* b1   = (const float*)d_in[4];
    const float* g1   = (const float*)d_in[5];
    const float* be1  = (const float*)d_in[6];
    const float* W2   = (const float*)d_in[7];
    const float* b2   = (const float*)d_in[8];
    const float* g2   = (const float*)d_in[9];
    const float* be2  = (const float*)d_in[10];
    const float* We1  = (const float*)d_in[11];
    const float* bb1  = (const float*)d_in[12];
    const float* gg1  = (const float*)d_in[13];
    const float* bbe1 = (const float*)d_in[14];
    const float* We2  = (const float*)d_in[15];
    const float* bb2  = (const float*)d_in[16];
    const float* gg2  = (const float*)d_in[17];
    const float* bbe2 = (const float*)d_in[18];
    float* out = (float*)d_out;

    // ws layout (floats/ints 4B-aligned, cd last)
    char* w = (char*)d_ws;
    float* part     = (float*)w;                     w += (size_t)B * NCHUNK * C * 4;
    int*   cnt      = (int*)w;                       w += (size_t)B * 4;
    int*   chunkpop = (int*)w;                       w += (size_t)B * NCHUNK * 4;
    int*   chunkoff = (int*)w;                       w += (size_t)B * NCHUNK * 4;
    unsigned short* cd = (unsigned short*)w;         // B*D ushort = 2.56 MB

    dim3 gridBD(NCHUNK, B);
    hipLaunchKernelGGL(k_count,   gridBD, dim3(CHUNK), 0, stream, mask, chunkpop);
    hipLaunchKernelGGL(k_scan,    dim3(B), dim3(128),  0, stream, chunkpop, chunkoff, cnt);
    hipLaunchKernelGGL(k_scatter, gridBD, dim3(CHUNK), 0, stream, mask, chunkoff, cd);
    hipLaunchKernelGGL(k_rows,    gridBD, dim3(CHUNK), 0, stream,
                       x, cd, cnt, fe, W1, b1, g1, be1, W2, b2, g2, be2, part);
    hipLaunchKernelGGL(k_enc,     dim3(B), dim3(EH),   0, stream,
                       part, cnt, We1, bb1, gg1, bbe1, We2, bb2, gg2, bbe2, out);
}